// Round 7
// baseline (80.840 us; speedup 1.0000x reference)
//
#include <hip/hip_runtime.h>

typedef unsigned short u16;
typedef short bf16x8 __attribute__((ext_vector_type(8)));
typedef u16 u16x8 __attribute__((ext_vector_type(8)));
typedef float f32x4 __attribute__((ext_vector_type(4)));

#define K_DIM 256
#define L_DIM 4096
#define NBATCH 4

static __device__ __forceinline__ u16 f2bf(float f) {
    unsigned u = __float_as_uint(f);
    unsigned r = (u + 0x7FFFu + ((u >> 16) & 1u)) >> 16;
    return (u16)r;
}
static __device__ __forceinline__ float bf2f(u16 v) {
    return __uint_as_float(((unsigned)v) << 16);
}
// fp32x8 -> bf16x8 fragment (RNE, identical rounding to the old cast kernel)
static __device__ __forceinline__ bf16x8 cvt8(const float* __restrict__ p) {
    const f32x4 a = *(const f32x4*)p;
    const f32x4 b = *(const f32x4*)(p + 4);
    bf16x8 r;
    #pragma unroll
    for (int j = 0; j < 4; ++j) r[j]     = (short)f2bf(a[j]);
    #pragma unroll
    for (int j = 0; j < 4; ++j) r[j + 4] = (short)f2bf(b[j]);
    return r;
}

// ---------------------------------------------------------------------------
// K1 fused_front: per block = 32 positions (half an image row) of one n.
// Phase a: depthwise 3x3 conv + bf16 cast of x, transposed into LDS tiles
//   tx_[32 pos][256 c], td_ (conv), with 16B-chunk XOR swizzle (^ row&7)
//   so GEMM-phase b128 reads hit the 8-way b128 floor instead of 16-way.
// Phase b: pin GEMM (val = x^T @ pin_w^T + b) and pw GEMM (om = dwc^T @ pw_w^T
//   + b) from the LDS tiles; B-fragments converted from fp32 weights in-reg.
// Outputs: val_b bf16 [NL][256], omb fp32 [NL][112]. No other intermediates.
// ---------------------------------------------------------------------------
__global__ __launch_bounds__(512, 4) void fused_front(
    const float* __restrict__ x, const float* __restrict__ dw_w,
    const float* __restrict__ dw_b, const float* __restrict__ pin_w,
    const float* __restrict__ pin_b, const float* __restrict__ pw_w,
    const float* __restrict__ pw_b, u16* __restrict__ val_b,
    float* __restrict__ omb)
{
    __shared__ u16 tx_[32 * 256];   // 16 KB, swizzled chunks
    __shared__ u16 td_[32 * 256];   // 16 KB

    const int half = blockIdx.x, h = blockIdx.y, n = blockIdx.z;
    const int t = threadIdx.x;
    const float* xn = x + (size_t)n * 256 * L_DIM;

    // ---- Phase a: conv + transpose-cast into swizzled LDS ----
    {
        const int w5 = t & 31;            // pos within half-row
        const int cg = t >> 5;            // 16 channel-groups of 16
        const int w = half * 32 + w5;     // global w
        const int wm = (w > 0) ? w - 1 : 0;
        const int wp = (w < 63) ? w + 1 : 63;
        const float lv = (w > 0) ? 1.f : 0.f;
        const float rv = (w < 63) ? 1.f : 0.f;

        #pragma unroll
        for (int j2 = 0; j2 < 2; ++j2) {
            u16x8 txv, tdv;
            #pragma unroll
            for (int jj = 0; jj < 8; ++jj) {
                const int c = cg * 16 + j2 * 8 + jj;
                const float* xc = xn + (size_t)c * L_DIM;
                const float* w9 = dw_w + c * 9;
                float s = dw_b[c];
                #pragma unroll
                for (int dy = 0; dy < 3; ++dy) {
                    const int hh = h + dy - 1;
                    if (hh < 0 || hh > 63) continue;   // block-uniform
                    const float* row = xc + hh * 64;
                    s = fmaf(row[wm] * lv, w9[dy*3 + 0], s);
                    s = fmaf(row[w],       w9[dy*3 + 1], s);
                    s = fmaf(row[wp] * rv, w9[dy*3 + 2], s);
                }
                txv[jj] = f2bf(xc[h*64 + w]);
                tdv[jj] = f2bf(s);
            }
            const int cj = cg * 2 + j2;                    // chunk 0..31
            const int off = w5 * 256 + ((cj ^ (w5 & 7)) * 8);
            *(u16x8*)&tx_[off] = txv;
            *(u16x8*)&td_[off] = tdv;
        }
    }
    __syncthreads();

    // ---- Phase b: pin + pw GEMMs ----
    const int wave = t >> 6, lane = t & 63;
    const int lr = lane & 15, lk = lane >> 4;

    f32x4 vacc[2][2];
    f32x4 oacc[2];
    #pragma unroll
    for (int m = 0; m < 2; ++m) {
        #pragma unroll
        for (int nn = 0; nn < 2; ++nn) vacc[m][nn] = (f32x4){0.f, 0.f, 0.f, 0.f};
        oacc[m] = (f32x4){0.f, 0.f, 0.f, 0.f};
    }
    const int pwrow = min(wave * 16 + lr, 111);   // wave 7 pads; clamp OOB

    #pragma unroll
    for (int kt = 0; kt < 8; ++kt) {
        bf16x8 af[2], ad[2];
        #pragma unroll
        for (int m = 0; m < 2; ++m) {
            const int row = m * 16 + lr;
            const int off = row * 256 + (((kt*4 + lk) ^ (row & 7)) * 8);
            af[m] = *(const bf16x8*)&tx_[off];
            ad[m] = *(const bf16x8*)&td_[off];
        }
        const bf16x8 bp0 = cvt8(pin_w + (size_t)(wave*32 + lr)      * K_DIM + kt*32 + lk*8);
        const bf16x8 bp1 = cvt8(pin_w + (size_t)(wave*32 + 16 + lr) * K_DIM + kt*32 + lk*8);
        const bf16x8 bw  = cvt8(pw_w  + (size_t)pwrow               * K_DIM + kt*32 + lk*8);
        #pragma unroll
        for (int m = 0; m < 2; ++m) {
            vacc[m][0] = __builtin_amdgcn_mfma_f32_16x16x32_bf16(af[m], bp0, vacc[m][0], 0, 0, 0);
            vacc[m][1] = __builtin_amdgcn_mfma_f32_16x16x32_bf16(af[m], bp1, vacc[m][1], 0, 0, 0);
            oacc[m]    = __builtin_amdgcn_mfma_f32_16x16x32_bf16(ad[m], bw,  oacc[m],    0, 0, 0);
        }
    }

    // ---- Epilogue: val (bf16) and om (fp32) rows ----
    const int l0 = h * 64 + half * 32;
    const int ch0 = wave * 32 + lr;
    const int ch2 = wave * 16 + lr;
    const float bv0 = pin_b[ch0], bv1 = pin_b[ch0 + 16];
    const float bw2 = (ch2 < 112) ? pw_b[ch2] : 0.f;
    #pragma unroll
    for (int m = 0; m < 2; ++m) {
        #pragma unroll
        for (int r = 0; r < 4; ++r) {
            const int l = l0 + m*16 + lk*4 + r;
            const size_t base = (size_t)n * L_DIM + l;
            val_b[base * 256 + ch0]      = f2bf(vacc[m][0][r] + bv0);
            val_b[base * 256 + ch0 + 16] = f2bf(vacc[m][1][r] + bv1);
            if (ch2 < 112) omb[base * 112 + ch2] = oacc[m][r] + bw2;
        }
    }
}

// ---------------------------------------------------------------------------
// K3: fused deformable gather + output projection.  [R6 structure; pout
// fragments now converted from fp32 pout_w in-register]
// 256 blocks x 512 thr. Block = one image row (64 pos) of one n,
// XCD-octile decode (h = xcd*8 + rd) for L2 locality of val row reuse.
// ---------------------------------------------------------------------------
__global__ __launch_bounds__(512, 2) void gather_pout(
    const float* __restrict__ om, const u16* __restrict__ val,
    const float* __restrict__ pout_w, const float* __restrict__ pout_b,
    float* __restrict__ out)
{
    __shared__ u16 sacc[64][264];
    const int blk = blockIdx.x;                // 0..255
    const int xcd = blk & 7, s = blk >> 3;     // s: 0..31
    const int n = s >> 3, rd = s & 7;
    const int h = xcd * 8 + rd;
    const int l0 = h * 64;
    const int t = threadIdx.x;
    const int wave = t >> 6, lane = t & 63;

    // ---- Phase A: deformable bilinear gather -> sacc ----
    {
        const int g = wave & 3, ph = wave >> 2;
        const int pq = lane >> 2;               // 0..15
        const int cl = (lane & 3) * 16;         // channel base within group
        const u16* valn = val + (size_t)n * L_DIM * 256;
        const u16* vb = valn + g * 64 + cl;
        const float ybase = (float)h - 1.f;

        #pragma unroll
        for (int i = 0; i < 2; ++i) {
            const int pos = ph * 32 + i * 16 + pq;   // 0..63
            const int l = l0 + pos;
            const float* omp = om + ((size_t)n * L_DIM + l) * 112 + g * 27;
            const float xb = (float)pos - 1.f;

            float a[16];
            #pragma unroll
            for (int j = 0; j < 16; ++j) a[j] = 0.f;

            #pragma unroll 3
            for (int p = 0; p < 9; ++p) {
                const float ox = omp[p*3 + 0];
                const float oy = omp[p*3 + 1];
                const float mk = omp[p*3 + 2];
                const float py = ybase + (float)(p / 3) + oy;
                const float px = xb + (float)(p % 3) + ox;
                const float y0 = floorf(py), x0 = floorf(px);
                const float fy = py - y0, fx = px - x0;
                const int iy0 = (int)y0, ix0 = (int)x0;
                const float wy[2] = {mk * (1.f - fy), mk * fy};
                const float wx[2] = {1.f - fx, fx};
                #pragma unroll
                for (int c4 = 0; c4 < 4; ++c4) {
                    const int dy = c4 >> 1, dx = c4 & 1;
                    const int iy = iy0 + dy, ix = ix0 + dx;
                    const bool ok = ((unsigned)iy < 64u) & ((unsigned)ix < 64u);
                    const float wgt = ok ? wy[dy] * wx[dx] : 0.f;
                    const int iyc = min(max(iy, 0), 63);
                    const int ixc = min(max(ix, 0), 63);
                    const u16* lp = vb + (size_t)(iyc * 64 + ixc) * 256;
                    const u16x8 v0 = *(const u16x8*)lp;
                    const u16x8 v1 = *(const u16x8*)(lp + 8);
                    #pragma unroll
                    for (int j = 0; j < 8; ++j) a[j]     = fmaf(wgt, bf2f(v0[j]), a[j]);
                    #pragma unroll
                    for (int j = 0; j < 8; ++j) a[j + 8] = fmaf(wgt, bf2f(v1[j]), a[j + 8]);
                }
            }
            u16x8 o0, o1;
            #pragma unroll
            for (int j = 0; j < 8; ++j) { o0[j] = f2bf(a[j]); o1[j] = f2bf(a[j + 8]); }
            *(u16x8*)(&sacc[pos][g*64 + cl])     = o0;
            *(u16x8*)(&sacc[pos][g*64 + cl + 8]) = o1;
        }
    }
    __syncthreads();

    // ---- Phase B: pout GEMM. Wave owns c-rows [wave*32, wave*32+32). ----
    const int lr = lane & 15, lk = lane >> 4;

    f32x4 acc4[2][4];
    #pragma unroll
    for (int m = 0; m < 2; ++m)
        #pragma unroll
        for (int nn = 0; nn < 4; ++nn) acc4[m][nn] = (f32x4){0.f, 0.f, 0.f, 0.f};

    #pragma unroll
    for (int kt = 0; kt < 8; ++kt) {
        bf16x8 bfr[4];
        #pragma unroll
        for (int nn = 0; nn < 4; ++nn)
            bfr[nn] = *(const bf16x8*)(&sacc[nn*16 + lr][kt*32 + lk*8]);
        #pragma unroll
        for (int m = 0; m < 2; ++m) {
            const bf16x8 af = cvt8(pout_w +
                (size_t)(wave*32 + m*16 + lr) * K_DIM + kt*32 + lk*8);
            #pragma unroll
            for (int nn = 0; nn < 4; ++nn)
                acc4[m][nn] = __builtin_amdgcn_mfma_f32_16x16x32_bf16(
                    af, bfr[nn], acc4[m][nn], 0, 0, 0);
        }
    }

    float* outn = out + (size_t)n * 256 * L_DIM;
    #pragma unroll
    for (int m = 0; m < 2; ++m) {
        #pragma unroll
        for (int nn = 0; nn < 4; ++nn) {
            const int col = l0 + nn*16 + lr;
            #pragma unroll
            for (int r = 0; r < 4; ++r) {
                const int row = wave*32 + m*16 + lk*4 + r;
                outn[(size_t)row * L_DIM + col] = acc4[m][nn][r] + pout_b[row];
            }
        }
    }
}

// ---------------------------------------------------------------------------
extern "C" void kernel_launch(void* const* d_in, const int* in_sizes, int n_in,
                              void* d_out, int out_size, void* d_ws, size_t ws_size,
                              hipStream_t stream) {
    const float* x      = (const float*)d_in[0];
    const float* dw_w   = (const float*)d_in[1];
    const float* dw_b   = (const float*)d_in[2];
    const float* pw_w   = (const float*)d_in[3];
    const float* pw_b   = (const float*)d_in[4];
    const float* pin_w  = (const float*)d_in[5];
    const float* pin_b  = (const float*)d_in[6];
    const float* pout_w = (const float*)d_in[7];
    const float* pout_b = (const float*)d_in[8];
    float* out = (float*)d_out;

    char* ws = (char*)d_ws;
    u16*   val_b = (u16*)ws;                    //  8,388,608 B
    float* omb   = (float*)(ws + 8388608);      //  7,340,032 B

    // K1: conv + transpose-cast + pin GEMM + pw GEMM (all row-local)
    fused_front<<<dim3(2, 64, NBATCH), 512, 0, stream>>>(
        x, dw_w, dw_b, pin_w, pin_b, pw_w, pw_b, val_b, omb);

    // K3: deformable gather + pout projection
    gather_pout<<<dim3(256), 512, 0, stream>>>(
        omb, val_b, pout_w, pout_b, out);
}

// Round 8
// 73.544 us; speedup vs baseline: 1.0992x; 1.0992x over previous
//
#include <hip/hip_runtime.h>

typedef unsigned short u16;
typedef short bf16x8 __attribute__((ext_vector_type(8)));
typedef u16 u16x8 __attribute__((ext_vector_type(8)));
typedef float f32x4 __attribute__((ext_vector_type(4)));

#define K_DIM 256
#define L_DIM 4096
#define NBATCH 4

static __device__ __forceinline__ u16 f2bf(float f) {
    unsigned u = __float_as_uint(f);
    unsigned r = (u + 0x7FFFu + ((u >> 16) & 1u)) >> 16;
    return (u16)r;
}
static __device__ __forceinline__ float bf2f(u16 v) {
    return __uint_as_float(((unsigned)v) << 16);
}

#define GLOAD16(g, l) __builtin_amdgcn_global_load_lds( \
    (const __attribute__((address_space(1))) void*)(g), \
    (__attribute__((address_space(3))) void*)(l), 16, 0, 0)

// ---------------------------------------------------------------------------
// K1: depthwise 3x3 conv + transpose + bf16 cast; weight casts folded in as
// extra blocks (blockIdx.x == 4).   [R6 verbatim]
// ---------------------------------------------------------------------------
__global__ __launch_bounds__(256) void prep_kernel(
    const float* __restrict__ x, const float* __restrict__ dw_w,
    const float* __restrict__ dw_b, const float* __restrict__ pin_w,
    const float* __restrict__ pw_w, const float* __restrict__ pout_w,
    u16* __restrict__ xb_t, u16* __restrict__ dwc_t,
    u16* __restrict__ pin_wb, u16* __restrict__ pw_wb,
    u16* __restrict__ pout_wb)
{
    if (blockIdx.x == 4) {                      // weight-cast blocks
        if (blockIdx.z != 0) return;
        const int end = (blockIdx.y + 1) * 2560;
        for (int k = blockIdx.y * 2560 + threadIdx.x; k < end; k += 256) {
            if (k < 65536) pin_wb[k] = f2bf(pin_w[k]);
            else if (k < 98304) {
                int j = k - 65536;
                pw_wb[j] = ((j >> 8) < 112) ? f2bf(pw_w[j]) : (u16)0;
            } else {
                int j = k - 98304;
                pout_wb[j] = f2bf(pout_w[j]);
            }
        }
        return;
    }

    __shared__ u16 tx_[64][66];
    __shared__ u16 td_[64][66];
    const int c0 = blockIdx.x * 64, h = blockIdx.y, n = blockIdx.z;
    const int t = threadIdx.x, w = t & 63, cq = t >> 6;
    const float* xn = x + (size_t)n * 256 * L_DIM;
    const int wm = (w > 0) ? w - 1 : 0;
    const int wp = (w < 63) ? w + 1 : 63;
    const float lv = (w > 0) ? 1.f : 0.f;
    const float rv = (w < 63) ? 1.f : 0.f;

    for (int i = 0; i < 16; ++i) {
        const int cl = i * 4 + cq, c = c0 + cl;
        const float* xc = xn + (size_t)c * L_DIM;
        const float* w9 = dw_w + c * 9;
        float s = dw_b[c];
        #pragma unroll
        for (int dy = 0; dy < 3; ++dy) {
            const int hh = h + dy - 1;
            if (hh < 0 || hh > 63) continue;   // block-uniform branch
            const float* row = xc + hh * 64;
            s = fmaf(row[wm] * lv, w9[dy*3 + 0], s);
            s = fmaf(row[w],       w9[dy*3 + 1], s);
            s = fmaf(row[wp] * rv, w9[dy*3 + 2], s);
        }
        tx_[w][cl] = f2bf(xc[h*64 + w]);
        td_[w][cl] = f2bf(s);
    }
    __syncthreads();
    const int cc = t & 63;
    for (int j = 0; j < 16; ++j) {
        const int wl = j * 4 + cq;
        const size_t o = ((size_t)n * L_DIM + h * 64 + wl) * 256 + c0 + cc;
        xb_t[o]  = tx_[wl][cc];
        dwc_t[o] = td_[wl][cc];
    }
}

// ---------------------------------------------------------------------------
// K2: pin + pw GEMMs in one dispatch.   [R6 verbatim]
// ---------------------------------------------------------------------------
__global__ __launch_bounds__(256) void gemm_dual(
    const u16* __restrict__ xb_t, const u16* __restrict__ dwc_t,
    const u16* __restrict__ pin_wb, const u16* __restrict__ pw_wb,
    const float* __restrict__ pin_b, const float* __restrict__ pw_b,
    u16* __restrict__ val_b, float* __restrict__ omb)
{
    __shared__ u16 lds[16384];
    const int bx = blockIdx.x;
    const bool isPw = (bx == 2);
    const u16* Ag = isPw ? dwc_t : xb_t;
    const u16* Bg = isPw ? pw_wb : pin_wb;
    const float* bias = isPw ? pw_b : pin_b;
    const int n0 = isPw ? 0 : bx * 128;
    const int Ncols = isPw ? 112 : 256;
    const int ldC = isPw ? 112 : 256;
    const int m0 = blockIdx.y * 128;

    const int t = threadIdx.x;
    const int wave = t >> 6, lane = t & 63;
    const int lr = lane & 15, lk = lane >> 4;
    const int wr = wave >> 1, wc = wave & 1;
    const int wbase = wave << 10;

    const int srow = t >> 2;
    const int scol = (t & 3) * 8;
    const u16* ga0 = Ag + (size_t)(m0 + srow)      * K_DIM + scol;
    const u16* ga1 = Ag + (size_t)(m0 + 64 + srow) * K_DIM + scol;
    const u16* gb0 = Bg + (size_t)(n0 + srow)      * K_DIM + scol;
    const u16* gb1 = Bg + (size_t)(n0 + 64 + srow) * K_DIM + scol;

    f32x4 acc[4][4];
    #pragma unroll
    for (int m = 0; m < 4; ++m)
        #pragma unroll
        for (int n = 0; n < 4; ++n) acc[m][n] = (f32x4){0.f, 0.f, 0.f, 0.f};

    auto stage = [&](int b, int kt) {
        const int ko = kt * 32;
        char* base = (char*)lds + b * 16384 + wbase;
        GLOAD16(ga0 + ko, base);
        GLOAD16(ga1 + ko, base + 4096);
        GLOAD16(gb0 + ko, base + 8192);
        GLOAD16(gb1 + ko, base + 12288);
    };

    stage(0, 0);
    asm volatile("s_waitcnt vmcnt(0)" ::: "memory");
    __syncthreads();

    for (int kt = 0; kt < 8; ++kt) {
        const int cur = kt & 1;
        if (kt < 7) stage(cur ^ 1, kt + 1);
        const char* la = (const char*)lds + cur * 16384;
        const char* lb = la + 8192;
        bf16x8 af[4], bfr[4];
        #pragma unroll
        for (int m = 0; m < 4; ++m)
            af[m] = *(const bf16x8*)(la + ((wr*64 + m*16 + lr) * 32 + lk * 8) * 2);
        #pragma unroll
        for (int n = 0; n < 4; ++n)
            bfr[n] = *(const bf16x8*)(lb + ((wc*64 + n*16 + lr) * 32 + lk * 8) * 2);
        #pragma unroll
        for (int m = 0; m < 4; ++m)
            #pragma unroll
            for (int n = 0; n < 4; ++n)
                acc[m][n] = __builtin_amdgcn_mfma_f32_16x16x32_bf16(
                    af[m], bfr[n], acc[m][n], 0, 0, 0);
        asm volatile("s_waitcnt vmcnt(0)" ::: "memory");
        __syncthreads();
    }

    #pragma unroll
    for (int m = 0; m < 4; ++m) {
        #pragma unroll
        for (int n = 0; n < 4; ++n) {
            const int col = n0 + wc*64 + n*16 + lr;
            if (col < Ncols) {
                const float bv = bias[col];
                #pragma unroll
                for (int r = 0; r < 4; ++r) {
                    const int row = m0 + wr*64 + m*16 + lk*4 + r;
                    const float o = acc[m][n][r] + bv;
                    const size_t off = (size_t)row * ldC + col;
                    if (isPw) omb[off] = o;
                    else      val_b[off] = f2bf(o);
                }
            }
        }
    }
}

// ---------------------------------------------------------------------------
// K3: fused deformable gather + output projection.  [R6 structure]
// ONE CHANGE vs R6: __launch_bounds__(512, 2) -> (512, 4).
// (512,2) = 2 waves/EU = 1 block/CU; the gather's ~300 MB of scattered
// 128B corner reads was latency-bound there. (512,4) = 2 blocks/CU doubles
// outstanding loads; VGPR cap 128 is above the kernel's ~90 peak.
// ---------------------------------------------------------------------------
__global__ __launch_bounds__(512, 4) void gather_pout(
    const float* __restrict__ om, const u16* __restrict__ val,
    const u16* __restrict__ pout_wb, const float* __restrict__ pout_b,
    float* __restrict__ out)
{
    __shared__ u16 sacc[64][264];
    const int blk = blockIdx.x;                // 0..255
    const int xcd = blk & 7, s = blk >> 3;     // s: 0..31
    const int n = s >> 3, rd = s & 7;
    const int h = xcd * 8 + rd;
    const int l0 = h * 64;
    const int t = threadIdx.x;
    const int wave = t >> 6, lane = t & 63;

    // ---- Phase A: deformable bilinear gather -> sacc ----
    {
        const int g = wave & 3, ph = wave >> 2;
        const int pq = lane >> 2;               // 0..15
        const int cl = (lane & 3) * 16;         // channel base within group
        const u16* valn = val + (size_t)n * L_DIM * 256;
        const u16* vb = valn + g * 64 + cl;
        const float ybase = (float)h - 1.f;

        #pragma unroll
        for (int i = 0; i < 2; ++i) {
            const int pos = ph * 32 + i * 16 + pq;   // 0..63
            const int l = l0 + pos;
            const float* omp = om + ((size_t)n * L_DIM + l) * 112 + g * 27;
            const float xb = (float)pos - 1.f;

            float a[16];
            #pragma unroll
            for (int j = 0; j < 16; ++j) a[j] = 0.f;

            #pragma unroll 3
            for (int p = 0; p < 9; ++p) {
                const float ox = omp[p*3 + 0];
                const float oy = omp[p*3 + 1];
                const float mk = omp[p*3 + 2];
                const float py = ybase + (float)(p / 3) + oy;
                const float px = xb + (float)(p % 3) + ox;
                const float y0 = floorf(py), x0 = floorf(px);
                const float fy = py - y0, fx = px - x0;
                const int iy0 = (int)y0, ix0 = (int)x0;
                const float wy[2] = {mk * (1.f - fy), mk * fy};
                const float wx[2] = {1.f - fx, fx};
                #pragma unroll
                for (int c4 = 0; c4 < 4; ++c4) {
                    const int dy = c4 >> 1, dx = c4 & 1;
                    const int iy = iy0 + dy, ix = ix0 + dx;
                    const bool ok = ((unsigned)iy < 64u) & ((unsigned)ix < 64u);
                    const float wgt = ok ? wy[dy] * wx[dx] : 0.f;
                    const int iyc = min(max(iy, 0), 63);
                    const int ixc = min(max(ix, 0), 63);
                    const u16* lp = vb + (size_t)(iyc * 64 + ixc) * 256;
                    const u16x8 v0 = *(const u16x8*)lp;
                    const u16x8 v1 = *(const u16x8*)(lp + 8);
                    #pragma unroll
                    for (int j = 0; j < 8; ++j) a[j]     = fmaf(wgt, bf2f(v0[j]), a[j]);
                    #pragma unroll
                    for (int j = 0; j < 8; ++j) a[j + 8] = fmaf(wgt, bf2f(v1[j]), a[j + 8]);
                }
            }
            u16x8 o0, o1;
            #pragma unroll
            for (int j = 0; j < 8; ++j) { o0[j] = f2bf(a[j]); o1[j] = f2bf(a[j + 8]); }
            *(u16x8*)(&sacc[pos][g*64 + cl])     = o0;
            *(u16x8*)(&sacc[pos][g*64 + cl + 8]) = o1;
        }
    }
    __syncthreads();

    // ---- Phase B: pout GEMM. Wave owns c-rows [wave*32, wave*32+32). ----
    const int lr = lane & 15, lk = lane >> 4;

    f32x4 acc4[2][4];
    #pragma unroll
    for (int m = 0; m < 2; ++m)
        #pragma unroll
        for (int nn = 0; nn < 4; ++nn) acc4[m][nn] = (f32x4){0.f, 0.f, 0.f, 0.f};

    #pragma unroll
    for (int kt = 0; kt < 8; ++kt) {
        bf16x8 bfr[4];
        #pragma unroll
        for (int nn = 0; nn < 4; ++nn)
            bfr[nn] = *(const bf16x8*)(&sacc[nn*16 + lr][kt*32 + lk*8]);
        #pragma unroll
        for (int m = 0; m < 2; ++m) {
            const bf16x8 af = *(const bf16x8*)(pout_wb +
                (size_t)(wave*32 + m*16 + lr) * K_DIM + kt*32 + lk*8);
            #pragma unroll
            for (int nn = 0; nn < 4; ++nn)
                acc4[m][nn] = __builtin_amdgcn_mfma_f32_16x16x32_bf16(
                    af, bfr[nn], acc4[m][nn], 0, 0, 0);
        }
    }

    float* outn = out + (size_t)n * 256 * L_DIM;
    #pragma unroll
    for (int m = 0; m < 2; ++m) {
        #pragma unroll
        for (int nn = 0; nn < 4; ++nn) {
            const int col = l0 + nn*16 + lr;
            #pragma unroll
            for (int r = 0; r < 4; ++r) {
                const int row = wave*32 + m*16 + lk*4 + r;
                outn[(size_t)row * L_DIM + col] = acc4[m][nn][r] + pout_b[row];
            }
        }
    }
}

// ---------------------------------------------------------------------------
extern "C" void kernel_launch(void* const* d_in, const int* in_sizes, int n_in,
                              void* d_out, int out_size, void* d_ws, size_t ws_size,
                              hipStream_t stream) {
    const float* x      = (const float*)d_in[0];
    const float* dw_w   = (const float*)d_in[1];
    const float* dw_b   = (const float*)d_in[2];
    const float* pw_w   = (const float*)d_in[3];
    const float* pw_b   = (const float*)d_in[4];
    const float* pin_w  = (const float*)d_in[5];
    const float* pin_b  = (const float*)d_in[6];
    const float* pout_w = (const float*)d_in[7];
    const float* pout_b = (const float*)d_in[8];
    float* out = (float*)d_out;

    char* ws = (char*)d_ws;
    u16*   xb_t    = (u16*)ws;                      //  8,388,608
    u16*   dwc_t   = (u16*)(ws + 8388608);          //  8,388,608
    u16*   val_b   = (u16*)(ws + 16777216);         //  8,388,608
    float* omb     = (float*)(ws + 25165824);       //  7,340,032
    u16*   pin_wb  = (u16*)(ws + 32505856);         //    131,072
    u16*   pw_wb   = (u16*)(ws + 32636928);         //     65,536 (128 rows)
    u16*   pout_wb = (u16*)(ws + 32702464);         //    131,072

    // K1: depthwise conv + transpose-cast + weight casts
    prep_kernel<<<dim3(5, 64, NBATCH), 256, 0, stream>>>(
        x, dw_w, dw_b, pin_w, pw_w, pout_w,
        xb_t, dwc_t, pin_wb, pw_wb, pout_wb);

    // K2: val = pin(x) [bf16], om = pw(dwc) [fp32]
    gemm_dual<<<dim3(3, 128), 256, 0, stream>>>(
        xb_t, dwc_t, pin_wb, pw_wb, pin_b, pw_b, val_b, omb);

    // K3: deformable gather + pout projection, 2 blocks/CU
    gather_pout<<<dim3(256), 512, 0, stream>>>(
        omb, val_b, pout_wb, pout_b, out);
}

// Round 9
// 70.120 us; speedup vs baseline: 1.1529x; 1.0488x over previous
//
#include <hip/hip_runtime.h>

typedef unsigned short u16;
typedef short bf16x8 __attribute__((ext_vector_type(8)));
typedef u16 u16x8 __attribute__((ext_vector_type(8)));
typedef float f32x4 __attribute__((ext_vector_type(4)));

#define K_DIM 256
#define L_DIM 4096
#define NBATCH 4

static __device__ __forceinline__ u16 f2bf(float f) {
    unsigned u = __float_as_uint(f);
    unsigned r = (u + 0x7FFFu + ((u >> 16) & 1u)) >> 16;
    return (u16)r;
}
static __device__ __forceinline__ float bf2f(u16 v) {
    return __uint_as_float(((unsigned)v) << 16);
}

#define GLOAD16(g, l) __builtin_amdgcn_global_load_lds( \
    (const __attribute__((address_space(1))) void*)(g), \
    (__attribute__((address_space(3))) void*)(l), 16, 0, 0)

// ---------------------------------------------------------------------------
// K1: depthwise 3x3 conv + transpose + bf16 cast; weight casts folded in as
// extra blocks (blockIdx.x == 4).   [unchanged]
// ---------------------------------------------------------------------------
__global__ __launch_bounds__(256) void prep_kernel(
    const float* __restrict__ x, const float* __restrict__ dw_w,
    const float* __restrict__ dw_b, const float* __restrict__ pin_w,
    const float* __restrict__ pw_w, const float* __restrict__ pout_w,
    u16* __restrict__ xb_t, u16* __restrict__ dwc_t,
    u16* __restrict__ pin_wb, u16* __restrict__ pw_wb,
    u16* __restrict__ pout_wb)
{
    if (blockIdx.x == 4) {                      // weight-cast blocks
        if (blockIdx.z != 0) return;
        const int end = (blockIdx.y + 1) * 2560;
        for (int k = blockIdx.y * 2560 + threadIdx.x; k < end; k += 256) {
            if (k < 65536) pin_wb[k] = f2bf(pin_w[k]);
            else if (k < 98304) {
                int j = k - 65536;
                pw_wb[j] = ((j >> 8) < 112) ? f2bf(pw_w[j]) : (u16)0;
            } else {
                int j = k - 98304;
                pout_wb[j] = f2bf(pout_w[j]);
            }
        }
        return;
    }

    __shared__ u16 tx_[64][66];
    __shared__ u16 td_[64][66];
    const int c0 = blockIdx.x * 64, h = blockIdx.y, n = blockIdx.z;
    const int t = threadIdx.x, w = t & 63, cq = t >> 6;
    const float* xn = x + (size_t)n * 256 * L_DIM;
    const int wm = (w > 0) ? w - 1 : 0;
    const int wp = (w < 63) ? w + 1 : 63;
    const float lv = (w > 0) ? 1.f : 0.f;
    const float rv = (w < 63) ? 1.f : 0.f;

    for (int i = 0; i < 16; ++i) {
        const int cl = i * 4 + cq, c = c0 + cl;
        const float* xc = xn + (size_t)c * L_DIM;
        const float* w9 = dw_w + c * 9;
        float s = dw_b[c];
        #pragma unroll
        for (int dy = 0; dy < 3; ++dy) {
            const int hh = h + dy - 1;
            if (hh < 0 || hh > 63) continue;   // block-uniform branch
            const float* row = xc + hh * 64;
            s = fmaf(row[wm] * lv, w9[dy*3 + 0], s);
            s = fmaf(row[w],       w9[dy*3 + 1], s);
            s = fmaf(row[wp] * rv, w9[dy*3 + 2], s);
        }
        tx_[w][cl] = f2bf(xc[h*64 + w]);
        td_[w][cl] = f2bf(s);
    }
    __syncthreads();
    const int cc = t & 63;
    for (int j = 0; j < 16; ++j) {
        const int wl = j * 4 + cq;
        const size_t o = ((size_t)n * L_DIM + h * 64 + wl) * 256 + c0 + cc;
        xb_t[o]  = tx_[wl][cc];
        dwc_t[o] = td_[wl][cc];
    }
}

// ---------------------------------------------------------------------------
// K2: pin + pw GEMMs in one dispatch.   [unchanged]
// ---------------------------------------------------------------------------
__global__ __launch_bounds__(256) void gemm_dual(
    const u16* __restrict__ xb_t, const u16* __restrict__ dwc_t,
    const u16* __restrict__ pin_wb, const u16* __restrict__ pw_wb,
    const float* __restrict__ pin_b, const float* __restrict__ pw_b,
    u16* __restrict__ val_b, float* __restrict__ omb)
{
    __shared__ u16 lds[16384];
    const int bx = blockIdx.x;
    const bool isPw = (bx == 2);
    const u16* Ag = isPw ? dwc_t : xb_t;
    const u16* Bg = isPw ? pw_wb : pin_wb;
    const float* bias = isPw ? pw_b : pin_b;
    const int n0 = isPw ? 0 : bx * 128;
    const int Ncols = isPw ? 112 : 256;
    const int ldC = isPw ? 112 : 256;
    const int m0 = blockIdx.y * 128;

    const int t = threadIdx.x;
    const int wave = t >> 6, lane = t & 63;
    const int lr = lane & 15, lk = lane >> 4;
    const int wr = wave >> 1, wc = wave & 1;
    const int wbase = wave << 10;

    const int srow = t >> 2;
    const int scol = (t & 3) * 8;
    const u16* ga0 = Ag + (size_t)(m0 + srow)      * K_DIM + scol;
    const u16* ga1 = Ag + (size_t)(m0 + 64 + srow) * K_DIM + scol;
    const u16* gb0 = Bg + (size_t)(n0 + srow)      * K_DIM + scol;
    const u16* gb1 = Bg + (size_t)(n0 + 64 + srow) * K_DIM + scol;

    f32x4 acc[4][4];
    #pragma unroll
    for (int m = 0; m < 4; ++m)
        #pragma unroll
        for (int n = 0; n < 4; ++n) acc[m][n] = (f32x4){0.f, 0.f, 0.f, 0.f};

    auto stage = [&](int b, int kt) {
        const int ko = kt * 32;
        char* base = (char*)lds + b * 16384 + wbase;
        GLOAD16(ga0 + ko, base);
        GLOAD16(ga1 + ko, base + 4096);
        GLOAD16(gb0 + ko, base + 8192);
        GLOAD16(gb1 + ko, base + 12288);
    };

    stage(0, 0);
    asm volatile("s_waitcnt vmcnt(0)" ::: "memory");
    __syncthreads();

    for (int kt = 0; kt < 8; ++kt) {
        const int cur = kt & 1;
        if (kt < 7) stage(cur ^ 1, kt + 1);
        const char* la = (const char*)lds + cur * 16384;
        const char* lb = la + 8192;
        bf16x8 af[4], bfr[4];
        #pragma unroll
        for (int m = 0; m < 4; ++m)
            af[m] = *(const bf16x8*)(la + ((wr*64 + m*16 + lr) * 32 + lk * 8) * 2);
        #pragma unroll
        for (int n = 0; n < 4; ++n)
            bfr[n] = *(const bf16x8*)(lb + ((wc*64 + n*16 + lr) * 32 + lk * 8) * 2);
        #pragma unroll
        for (int m = 0; m < 4; ++m)
            #pragma unroll
            for (int n = 0; n < 4; ++n)
                acc[m][n] = __builtin_amdgcn_mfma_f32_16x16x32_bf16(
                    af[m], bfr[n], acc[m][n], 0, 0, 0);
        asm volatile("s_waitcnt vmcnt(0)" ::: "memory");
        __syncthreads();
    }

    #pragma unroll
    for (int m = 0; m < 4; ++m) {
        #pragma unroll
        for (int n = 0; n < 4; ++n) {
            const int col = n0 + wc*64 + n*16 + lr;
            if (col < Ncols) {
                const float bv = bias[col];
                #pragma unroll
                for (int r = 0; r < 4; ++r) {
                    const int row = m0 + wr*64 + m*16 + lk*4 + r;
                    const float o = acc[m][n][r] + bv;
                    const size_t off = (size_t)row * ldC + col;
                    if (isPw) omb[off] = o;
                    else      val_b[off] = f2bf(o);
                }
            }
        }
    }
}

// ---------------------------------------------------------------------------
// K3: fused deformable gather + output projection, wave-rich version.
// Grid 512 x 512 thr, 2 blocks/CU -> 16 waves/CU (4/SIMD), double R6/R8.
// Block = 32 positions (half-row) of one n; XCD-octile decode on h.
// Gather: slot = i*512 + t; pos = slot>>5, g = (slot>>3)&3, ch = (slot&7)*8.
//   8 ch/lane -> ONE u16x8 load per corner (72 loads/lane, was 144).
//   Per-channel fma order identical to R6/R8 -> bitwise-same result.
// Pout: wave owns 32 c-rows x 32 cols; 32 MFMA/wave.
// ---------------------------------------------------------------------------
__global__ __launch_bounds__(512, 4) void gather_pout(
    const float* __restrict__ om, const u16* __restrict__ val,
    const u16* __restrict__ pout_wb, const float* __restrict__ pout_b,
    float* __restrict__ out)
{
    __shared__ u16 sacc[32][264];
    const int blk = blockIdx.x;                // 0..511
    const int xcd = blk & 7, s = blk >> 3;     // s: 0..63
    const int half = s & 1, rd = (s >> 1) & 7, n = s >> 4;
    const int h = xcd * 8 + rd;
    const int l0 = h * 64 + half * 32;
    const int t = threadIdx.x;

    // ---- Phase A: deformable bilinear gather -> sacc ----
    {
        const u16* valn = val + (size_t)n * L_DIM * 256;
        const float ybase = (float)h - 1.f;

        #pragma unroll
        for (int i = 0; i < 2; ++i) {
            const int slot = i * 512 + t;
            const int pos = slot >> 5;              // 0..31
            const int g = (slot >> 3) & 3;
            const int ch = (slot & 7) * 8;
            const int l = l0 + pos;
            const float* omp = om + ((size_t)n * L_DIM + l) * 112 + g * 27;
            const u16* vb = valn + g * 64 + ch;
            const float xb = (float)(l & 63) - 1.f;

            float a[8];
            #pragma unroll
            for (int j = 0; j < 8; ++j) a[j] = 0.f;

            #pragma unroll 3
            for (int p = 0; p < 9; ++p) {
                const float ox = omp[p*3 + 0];
                const float oy = omp[p*3 + 1];
                const float mk = omp[p*3 + 2];
                const float py = ybase + (float)(p / 3) + oy;
                const float px = xb + (float)(p % 3) + ox;
                const float y0 = floorf(py), x0 = floorf(px);
                const float fy = py - y0, fx = px - x0;
                const int iy0 = (int)y0, ix0 = (int)x0;
                const float wy[2] = {mk * (1.f - fy), mk * fy};
                const float wx[2] = {1.f - fx, fx};
                #pragma unroll
                for (int c4 = 0; c4 < 4; ++c4) {
                    const int dy = c4 >> 1, dx = c4 & 1;
                    const int iy = iy0 + dy, ix = ix0 + dx;
                    const bool ok = ((unsigned)iy < 64u) & ((unsigned)ix < 64u);
                    const float wgt = ok ? wy[dy] * wx[dx] : 0.f;
                    const int iyc = min(max(iy, 0), 63);
                    const int ixc = min(max(ix, 0), 63);
                    const u16x8 v = *(const u16x8*)(vb + (size_t)(iyc * 64 + ixc) * 256);
                    #pragma unroll
                    for (int j = 0; j < 8; ++j) a[j] = fmaf(wgt, bf2f(v[j]), a[j]);
                }
            }
            u16x8 o;
            #pragma unroll
            for (int j = 0; j < 8; ++j) o[j] = f2bf(a[j]);
            *(u16x8*)(&sacc[pos][g*64 + ch]) = o;
        }
    }
    __syncthreads();

    // ---- Phase B: pout GEMM. Wave owns c-rows [wave*32, wave*32+32) x 32 cols ----
    const int wave = t >> 6, lane = t & 63;
    const int lr = lane & 15, lk = lane >> 4;

    f32x4 acc4[2][2];
    #pragma unroll
    for (int m = 0; m < 2; ++m)
        #pragma unroll
        for (int nn = 0; nn < 2; ++nn) acc4[m][nn] = (f32x4){0.f, 0.f, 0.f, 0.f};

    #pragma unroll
    for (int kt = 0; kt < 8; ++kt) {
        bf16x8 bfr[2];
        #pragma unroll
        for (int nn = 0; nn < 2; ++nn)
            bfr[nn] = *(const bf16x8*)(&sacc[nn*16 + lr][kt*32 + lk*8]);
        #pragma unroll
        for (int m = 0; m < 2; ++m) {
            const bf16x8 af = *(const bf16x8*)(pout_wb +
                (size_t)(wave*32 + m*16 + lr) * K_DIM + kt*32 + lk*8);
            #pragma unroll
            for (int nn = 0; nn < 2; ++nn)
                acc4[m][nn] = __builtin_amdgcn_mfma_f32_16x16x32_bf16(
                    af, bfr[nn], acc4[m][nn], 0, 0, 0);
        }
    }

    float* outn = out + (size_t)n * 256 * L_DIM;
    #pragma unroll
    for (int m = 0; m < 2; ++m) {
        #pragma unroll
        for (int nn = 0; nn < 2; ++nn) {
            const int col = l0 + nn*16 + lr;
            #pragma unroll
            for (int r = 0; r < 4; ++r) {
                const int row = wave*32 + m*16 + lk*4 + r;
                outn[(size_t)row * L_DIM + col] = acc4[m][nn][r] + pout_b[row];
            }
        }
    }
}

// ---------------------------------------------------------------------------
extern "C" void kernel_launch(void* const* d_in, const int* in_sizes, int n_in,
                              void* d_out, int out_size, void* d_ws, size_t ws_size,
                              hipStream_t stream) {
    const float* x      = (const float*)d_in[0];
    const float* dw_w   = (const float*)d_in[1];
    const float* dw_b   = (const float*)d_in[2];
    const float* pw_w   = (const float*)d_in[3];
    const float* pw_b   = (const float*)d_in[4];
    const float* pin_w  = (const float*)d_in[5];
    const float* pin_b  = (const float*)d_in[6];
    const float* pout_w = (const float*)d_in[7];
    const float* pout_b = (const float*)d_in[8];
    float* out = (float*)d_out;

    char* ws = (char*)d_ws;
    u16*   xb_t    = (u16*)ws;                      //  8,388,608
    u16*   dwc_t   = (u16*)(ws + 8388608);          //  8,388,608
    u16*   val_b   = (u16*)(ws + 16777216);         //  8,388,608
    float* omb     = (float*)(ws + 25165824);       //  7,340,032
    u16*   pin_wb  = (u16*)(ws + 32505856);         //    131,072
    u16*   pw_wb   = (u16*)(ws + 32636928);         //     65,536 (128 rows)
    u16*   pout_wb = (u16*)(ws + 32702464);         //    131,072

    // K1: depthwise conv + transpose-cast + weight casts
    prep_kernel<<<dim3(5, 64, NBATCH), 256, 0, stream>>>(
        x, dw_w, dw_b, pin_w, pw_w, pout_w,
        xb_t, dwc_t, pin_wb, pw_wb, pout_wb);

    // K2: val = pin(x) [bf16], om = pw(dwc) [fp32]
    gemm_dual<<<dim3(3, 128), 256, 0, stream>>>(
        xb_t, dwc_t, pin_wb, pw_wb, pin_b, pw_b, val_b, omb);

    // K3: deformable gather + pout projection, 512 blocks, 16 waves/CU
    gather_pout<<<dim3(512), 512, 0, stream>>>(
        omb, val_b, pout_wb, pout_b, out);
}

// Round 10
// 58.131 us; speedup vs baseline: 1.3907x; 1.2062x over previous
//
#include <hip/hip_runtime.h>

typedef unsigned short u16;
typedef short bf16x8 __attribute__((ext_vector_type(8)));
typedef u16 u16x8 __attribute__((ext_vector_type(8)));
typedef float f32x4 __attribute__((ext_vector_type(4)));

#define K_DIM 256
#define L_DIM 4096
#define NBATCH 4

static __device__ __forceinline__ u16 f2bf(float f) {
    unsigned u = __float_as_uint(f);
    unsigned r = (u + 0x7FFFu + ((u >> 16) & 1u)) >> 16;
    return (u16)r;
}
static __device__ __forceinline__ float bf2f(u16 v) {
    return __uint_as_float(((unsigned)v) << 16);
}

#define GLOAD16(g, l) __builtin_amdgcn_global_load_lds( \
    (const __attribute__((address_space(1))) void*)(g), \
    (__attribute__((address_space(3))) void*)(l), 16, 0, 0)

// ---------------------------------------------------------------------------
// K1: depthwise 3x3 conv + transpose + bf16 cast; weight casts folded in.
// Vectorized: thread owns 4 w x 4 c; each conv row = one float4 + 2 clamped
// edge scalars (36 load instrs/thread vs 160 scalar). Same fma order/clamps
// as before -> bitwise-identical output.
// ---------------------------------------------------------------------------
__global__ __launch_bounds__(256) void prep_kernel(
    const float* __restrict__ x, const float* __restrict__ dw_w,
    const float* __restrict__ dw_b, const float* __restrict__ pin_w,
    const float* __restrict__ pw_w, const float* __restrict__ pout_w,
    u16* __restrict__ xb_t, u16* __restrict__ dwc_t,
    u16* __restrict__ pin_wb, u16* __restrict__ pw_wb,
    u16* __restrict__ pout_wb)
{
    if (blockIdx.x == 4) {                      // weight-cast blocks
        if (blockIdx.z != 0) return;
        const int end = (blockIdx.y + 1) * 2560;
        for (int k = blockIdx.y * 2560 + threadIdx.x; k < end; k += 256) {
            if (k < 65536) pin_wb[k] = f2bf(pin_w[k]);
            else if (k < 98304) {
                int j = k - 65536;
                pw_wb[j] = ((j >> 8) < 112) ? f2bf(pw_w[j]) : (u16)0;
            } else {
                int j = k - 98304;
                pout_wb[j] = f2bf(pout_w[j]);
            }
        }
        return;
    }

    __shared__ u16 tx_[64][66];
    __shared__ u16 td_[64][66];
    const int c0 = blockIdx.x * 64, h = blockIdx.y, n = blockIdx.z;
    const int t = threadIdx.x;
    const float* xn = x + (size_t)n * 256 * L_DIM;

    const int w4 = (t & 15) * 4;          // 0..60
    const int cs = t >> 4;                // 0..15

    #pragma unroll
    for (int j = 0; j < 4; ++j) {
        const int cl = cs * 4 + j, c = c0 + cl;
        const float* xc = xn + (size_t)c * L_DIM;
        const float* w9 = dw_w + c * 9;

        float s[4];
        const float bv = dw_b[c];
        #pragma unroll
        for (int k = 0; k < 4; ++k) s[k] = bv;
        f32x4 center;

        #pragma unroll
        for (int dy = 0; dy < 3; ++dy) {
            const int hh = h + dy - 1;
            if (hh < 0 || hh > 63) continue;        // block-uniform
            const float* row = xc + hh * 64;
            const f32x4 m = *(const f32x4*)(row + w4);
            const float flv = row[(w4 > 0) ? w4 - 1 : 0];
            const float frv = row[(w4 + 4 < 64) ? w4 + 4 : 63];
            if (dy == 1) center = m;
            #pragma unroll
            for (int k = 0; k < 4; ++k) {
                const int w = w4 + k;
                const float lv = (w > 0) ? 1.f : 0.f;
                const float rv = (w < 63) ? 1.f : 0.f;
                const float xm = (k == 0) ? flv : m[k - 1];
                const float xp = (k == 3) ? frv : m[k + 1];
                s[k] = fmaf(xm * lv, w9[dy*3 + 0], s[k]);
                s[k] = fmaf(m[k],    w9[dy*3 + 1], s[k]);
                s[k] = fmaf(xp * rv, w9[dy*3 + 2], s[k]);
            }
        }
        #pragma unroll
        for (int k = 0; k < 4; ++k) {
            tx_[w4 + k][cl] = f2bf(center[k]);
            td_[w4 + k][cl] = f2bf(s[k]);
        }
    }
    __syncthreads();

    const int cc = t & 63, cq = t >> 6;
    for (int j = 0; j < 16; ++j) {
        const int wl = j * 4 + cq;
        const size_t o = ((size_t)n * L_DIM + h * 64 + wl) * 256 + c0 + cc;
        xb_t[o]  = tx_[wl][cc];
        dwc_t[o] = td_[wl][cc];
    }
}

// ---------------------------------------------------------------------------
// K2: pin + pw GEMMs in one dispatch.   [unchanged]
// ---------------------------------------------------------------------------
__global__ __launch_bounds__(256) void gemm_dual(
    const u16* __restrict__ xb_t, const u16* __restrict__ dwc_t,
    const u16* __restrict__ pin_wb, const u16* __restrict__ pw_wb,
    const float* __restrict__ pin_b, const float* __restrict__ pw_b,
    u16* __restrict__ val_b, float* __restrict__ omb)
{
    __shared__ u16 lds[16384];
    const int bx = blockIdx.x;
    const bool isPw = (bx == 2);
    const u16* Ag = isPw ? dwc_t : xb_t;
    const u16* Bg = isPw ? pw_wb : pin_wb;
    const float* bias = isPw ? pw_b : pin_b;
    const int n0 = isPw ? 0 : bx * 128;
    const int Ncols = isPw ? 112 : 256;
    const int ldC = isPw ? 112 : 256;
    const int m0 = blockIdx.y * 128;

    const int t = threadIdx.x;
    const int wave = t >> 6, lane = t & 63;
    const int lr = lane & 15, lk = lane >> 4;
    const int wr = wave >> 1, wc = wave & 1;
    const int wbase = wave << 10;

    const int srow = t >> 2;
    const int scol = (t & 3) * 8;
    const u16* ga0 = Ag + (size_t)(m0 + srow)      * K_DIM + scol;
    const u16* ga1 = Ag + (size_t)(m0 + 64 + srow) * K_DIM + scol;
    const u16* gb0 = Bg + (size_t)(n0 + srow)      * K_DIM + scol;
    const u16* gb1 = Bg + (size_t)(n0 + 64 + srow) * K_DIM + scol;

    f32x4 acc[4][4];
    #pragma unroll
    for (int m = 0; m < 4; ++m)
        #pragma unroll
        for (int n = 0; n < 4; ++n) acc[m][n] = (f32x4){0.f, 0.f, 0.f, 0.f};

    auto stage = [&](int b, int kt) {
        const int ko = kt * 32;
        char* base = (char*)lds + b * 16384 + wbase;
        GLOAD16(ga0 + ko, base);
        GLOAD16(ga1 + ko, base + 4096);
        GLOAD16(gb0 + ko, base + 8192);
        GLOAD16(gb1 + ko, base + 12288);
    };

    stage(0, 0);
    asm volatile("s_waitcnt vmcnt(0)" ::: "memory");
    __syncthreads();

    for (int kt = 0; kt < 8; ++kt) {
        const int cur = kt & 1;
        if (kt < 7) stage(cur ^ 1, kt + 1);
        const char* la = (const char*)lds + cur * 16384;
        const char* lb = la + 8192;
        bf16x8 af[4], bfr[4];
        #pragma unroll
        for (int m = 0; m < 4; ++m)
            af[m] = *(const bf16x8*)(la + ((wr*64 + m*16 + lr) * 32 + lk * 8) * 2);
        #pragma unroll
        for (int n = 0; n < 4; ++n)
            bfr[n] = *(const bf16x8*)(lb + ((wc*64 + n*16 + lr) * 32 + lk * 8) * 2);
        #pragma unroll
        for (int m = 0; m < 4; ++m)
            #pragma unroll
            for (int n = 0; n < 4; ++n)
                acc[m][n] = __builtin_amdgcn_mfma_f32_16x16x32_bf16(
                    af[m], bfr[n], acc[m][n], 0, 0, 0);
        asm volatile("s_waitcnt vmcnt(0)" ::: "memory");
        __syncthreads();
    }

    #pragma unroll
    for (int m = 0; m < 4; ++m) {
        #pragma unroll
        for (int n = 0; n < 4; ++n) {
            const int col = n0 + wc*64 + n*16 + lr;
            if (col < Ncols) {
                const float bv = bias[col];
                #pragma unroll
                for (int r = 0; r < 4; ++r) {
                    const int row = m0 + wr*64 + m*16 + lk*4 + r;
                    const float o = acc[m][n][r] + bv;
                    const size_t off = (size_t)row * ldC + col;
                    if (isPw) omb[off] = o;
                    else      val_b[off] = f2bf(o);
                }
            }
        }
    }
}

// ---------------------------------------------------------------------------
// K3: fused deformable gather + output projection.  [R9 structure]
// NEW: block's om slice (32 pos x 112 f32 = 14 KB, contiguous) staged into
// LDS via global_load_lds; gather reads om as LDS broadcasts instead of 54
// scattered scalar L2 loads per lane.
// ---------------------------------------------------------------------------
__global__ __launch_bounds__(512, 4) void gather_pout(
    const float* __restrict__ om, const u16* __restrict__ val,
    const u16* __restrict__ pout_wb, const float* __restrict__ pout_b,
    float* __restrict__ out)
{
    __shared__ u16 sacc[32][264];
    __shared__ float som[4096];                // 16 KB (14 KB used)
    const int blk = blockIdx.x;                // 0..511
    const int xcd = blk & 7, s = blk >> 3;     // s: 0..63
    const int half = s & 1, rd = (s >> 1) & 7, n = s >> 4;
    const int h = xcd * 8 + rd;
    const int l0 = h * 64 + half * 32;
    const int t = threadIdx.x;

    // stage om slice: 2 x (512 thr x 16 B); wave-uniform LDS base + lane*16
    {
        const float* omsrc = om + ((size_t)n * L_DIM + l0) * 112;
        const int wb = (t >> 6) << 10;         // wave byte base
        GLOAD16(omsrc + t * 4,        (char*)som + wb);
        GLOAD16(omsrc + 2048 + t * 4, (char*)som + 8192 + wb);
        asm volatile("s_waitcnt vmcnt(0)" ::: "memory");
        __syncthreads();
    }

    // ---- Phase A: deformable bilinear gather -> sacc ----
    {
        const u16* valn = val + (size_t)n * L_DIM * 256;
        const float ybase = (float)h - 1.f;

        #pragma unroll
        for (int i = 0; i < 2; ++i) {
            const int slot = i * 512 + t;
            const int pos = slot >> 5;              // 0..31
            const int g = (slot >> 3) & 3;
            const int ch = (slot & 7) * 8;
            const int l = l0 + pos;
            const float* omp = som + pos * 112 + g * 27;
            const u16* vb = valn + g * 64 + ch;
            const float xb = (float)(l & 63) - 1.f;

            float a[8];
            #pragma unroll
            for (int j = 0; j < 8; ++j) a[j] = 0.f;

            #pragma unroll 3
            for (int p = 0; p < 9; ++p) {
                const float ox = omp[p*3 + 0];
                const float oy = omp[p*3 + 1];
                const float mk = omp[p*3 + 2];
                const float py = ybase + (float)(p / 3) + oy;
                const float px = xb + (float)(p % 3) + ox;
                const float y0 = floorf(py), x0 = floorf(px);
                const float fy = py - y0, fx = px - x0;
                const int iy0 = (int)y0, ix0 = (int)x0;
                const float wy[2] = {mk * (1.f - fy), mk * fy};
                const float wx[2] = {1.f - fx, fx};
                #pragma unroll
                for (int c4 = 0; c4 < 4; ++c4) {
                    const int dy = c4 >> 1, dx = c4 & 1;
                    const int iy = iy0 + dy, ix = ix0 + dx;
                    const bool ok = ((unsigned)iy < 64u) & ((unsigned)ix < 64u);
                    const float wgt = ok ? wy[dy] * wx[dx] : 0.f;
                    const int iyc = min(max(iy, 0), 63);
                    const int ixc = min(max(ix, 0), 63);
                    const u16x8 v = *(const u16x8*)(vb + (size_t)(iyc * 64 + ixc) * 256);
                    #pragma unroll
                    for (int j = 0; j < 8; ++j) a[j] = fmaf(wgt, bf2f(v[j]), a[j]);
                }
            }
            u16x8 o;
            #pragma unroll
            for (int j = 0; j < 8; ++j) o[j] = f2bf(a[j]);
            *(u16x8*)(&sacc[pos][g*64 + ch]) = o;
        }
    }
    __syncthreads();

    // ---- Phase B: pout GEMM. Wave owns c-rows [wave*32, wave*32+32) x 32 cols ----
    const int wave = t >> 6, lane = t & 63;
    const int lr = lane & 15, lk = lane >> 4;

    f32x4 acc4[2][2];
    #pragma unroll
    for (int m = 0; m < 2; ++m)
        #pragma unroll
        for (int nn = 0; nn < 2; ++nn) acc4[m][nn] = (f32x4){0.f, 0.f, 0.f, 0.f};

    #pragma unroll
    for (int kt = 0; kt < 8; ++kt) {
        bf16x8 bfr[2];
        #pragma unroll
        for (int nn = 0; nn < 2; ++nn)
            bfr[nn] = *(const bf16x8*)(&sacc[nn*16 + lr][kt*32 + lk*8]);
        #pragma unroll
        for (int m = 0; m < 2; ++m) {
            const bf16x8 af = *(const bf16x8*)(pout_wb +
                (size_t)(wave*32 + m*16 + lr) * K_DIM + kt*32 + lk*8);
            #pragma unroll
            for (int nn = 0; nn < 2; ++nn)
                acc4[m][nn] = __builtin_amdgcn_mfma_f32_16x16x32_bf16(
                    af, bfr[nn], acc4[m][nn], 0, 0, 0);
        }
    }

    float* outn = out + (size_t)n * 256 * L_DIM;
    #pragma unroll
    for (int m = 0; m < 2; ++m) {
        #pragma unroll
        for (int nn = 0; nn < 2; ++nn) {
            const int col = l0 + nn*16 + lr;
            #pragma unroll
            for (int r = 0; r < 4; ++r) {
                const int row = wave*32 + m*16 + lk*4 + r;
                outn[(size_t)row * L_DIM + col] = acc4[m][nn][r] + pout_b[row];
            }
        }
    }
}

// ---------------------------------------------------------------------------
extern "C" void kernel_launch(void* const* d_in, const int* in_sizes, int n_in,
                              void* d_out, int out_size, void* d_ws, size_t ws_size,
                              hipStream_t stream) {
    const float* x      = (const float*)d_in[0];
    const float* dw_w   = (const float*)d_in[1];
    const float* dw_b   = (const float*)d_in[2];
    const float* pw_w   = (const float*)d_in[3];
    const float* pw_b   = (const float*)d_in[4];
    const float* pin_w  = (const float*)d_in[5];
    const float* pin_b  = (const float*)d_in[6];
    const float* pout_w = (const float*)d_in[7];
    const float* pout_b = (const float*)d_in[8];
    float* out = (float*)d_out;

    char* ws = (char*)d_ws;
    u16*   xb_t    = (u16*)ws;                      //  8,388,608
    u16*   dwc_t   = (u16*)(ws + 8388608);          //  8,388,608
    u16*   val_b   = (u16*)(ws + 16777216);         //  8,388,608
    float* omb     = (float*)(ws + 25165824);       //  7,340,032
    u16*   pin_wb  = (u16*)(ws + 32505856);         //    131,072
    u16*   pw_wb   = (u16*)(ws + 32636928);         //     65,536 (128 rows)
    u16*   pout_wb = (u16*)(ws + 32702464);         //    131,072

    // K1: depthwise conv + transpose-cast + weight casts (vectorized loads)
    prep_kernel<<<dim3(5, 64, NBATCH), 256, 0, stream>>>(
        x, dw_w, dw_b, pin_w, pw_w, pout_w,
        xb_t, dwc_t, pin_wb, pw_wb, pout_wb);

    // K2: val = pin(x) [bf16], om = pw(dwc) [fp32]
    gemm_dual<<<dim3(3, 128), 256, 0, stream>>>(
        xb_t, dwc_t, pin_wb, pw_wb, pin_b, pw_b, val_b, omb);

    // K3: deformable gather (om in LDS) + pout projection
    gather_pout<<<dim3(512), 512, 0, stream>>>(
        omb, val_b, pout_wb, pout_b, out);
}